// Round 12
// baseline (76.976 us; speedup 1.0000x reference)
//
#include <hip/hip_runtime.h>
#include <hip/hip_bf16.h>

// DEC ClusteringLayer: q[i][j] = (1/(1+||x_i-c_j||^2)) / rowsum, ALPHA=1.
// Round 12: BM=128, BK=64. 8 iterations, 32 MFMA + 16 LDS reads per wave per
// barrier interval (2x R11). B images pair-double-buffered (4 x 16KB); A tile
// (128x64 bf16, 16KB) single-buffered with a cheap lgkm-only barrier before
// overwrite. One vm-drain barrier per iter (8 total), draining only 1-iter-old
// B DMAs; X issued before the GLDS pair so CVT's X-wait leaves DMAs in flight.
// LDS exactly 80KB -> 2 blocks/CU; s_x2/s_rs alias B-buf 0 post-loop.

typedef __attribute__((ext_vector_type(8))) short short8v;
typedef __attribute__((ext_vector_type(4))) float f32x4;

#define DDIM 512
#define KCL  256
#define BM   128
#define NT   512
#define NIMG 16          // K-chunk images of 32
#define BTILE 8192       // shorts per fragment-order B image (256 x 32)

__device__ __forceinline__ short f2bf(float f) {
    __hip_bfloat16 h = __float2bfloat16(f);
    return __builtin_bit_cast(short, h);
}

__device__ __forceinline__ void glds16(const void* g, void* l) {
    __builtin_amdgcn_global_load_lds(
        (const __attribute__((address_space(1))) unsigned int*)g,
        (__attribute__((address_space(3))) unsigned int*)l, 16, 0, 0);
}

// ---- pre-kernel: blocks 0..63 pack clusters -> bf16 fragment-order images;
//      blocks 64..79 compute ||c||^2 ----
__global__ void prep(const float* __restrict__ cl, short* __restrict__ wsB,
                     float* __restrict__ wsC2) {
    const int t = threadIdx.x;
    if (blockIdx.x < 64) {
        const int u = blockIdx.x * 256 + t;
        const int img = u >> 10, gi = u & 1023;
        const int g = gi >> 6, lq = (gi >> 4) & 3, l15 = gi & 15;
        const float* src = cl + (size_t)(g * 16 + l15) * DDIM + img * 32 + lq * 8;
        float4 a = *(const float4*)src;
        float4 b = *(const float4*)(src + 4);
        short8v s;
        s[0]=f2bf(a.x); s[1]=f2bf(a.y); s[2]=f2bf(a.z); s[3]=f2bf(a.w);
        s[4]=f2bf(b.x); s[5]=f2bf(b.y); s[6]=f2bf(b.z); s[7]=f2bf(b.w);
        *(short8v*)&wsB[(size_t)u * 8] = s;
    } else {
        const int cidx = (blockIdx.x - 64) * 16 + (t >> 4);
        const int j = t & 15;
        const float* src = cl + (size_t)cidx * DDIM + j * 32;
        float s = 0.f;
#pragma unroll
        for (int i = 0; i < 8; ++i) {
            float4 v = ((const float4*)src)[i];
            s += v.x*v.x + v.y*v.y + v.z*v.z + v.w*v.w;
        }
        s += __shfl_xor(s, 1); s += __shfl_xor(s, 2);
        s += __shfl_xor(s, 4); s += __shfl_xor(s, 8);
        if (j == 0) wsC2[cidx] = s;
    }
}

#define SFENCE()  __builtin_amdgcn_sched_barrier(0)
#define BARLGKM() asm volatile("s_waitcnt lgkmcnt(0)\ns_barrier" ::: "memory")
#define BARV0()   asm volatile("s_waitcnt vmcnt(0) lgkmcnt(0)\ns_barrier" ::: "memory")

__global__ __launch_bounds__(NT, 4)
void dec_main(const float* __restrict__ x, const short* __restrict__ wsB,
              const float* __restrict__ wsC2, float* __restrict__ out) {
    __shared__ __align__(16) short lB4[4][BTILE];   // 64 KB: B images, pair-dbuf
    __shared__ __align__(16) short lA[8192];        // 16 KB: A tile 128 x 64 bf16
    float* const s_x2 = (float*)&lB4[0][0];         // aliased post-loop
    float* const s_rs = ((float*)&lB4[0][0]) + BM;

    const int t = threadIdx.x, lane = t & 63, w = t >> 6;
    const int rg = w >> 2, cg = w & 3;              // 2 row-groups x 4 col-groups
    const int l15 = lane & 15, lq = lane >> 4;
    const int row0 = blockIdx.x * BM;

    // ---- A staging: thread t covers row R=t>>2, 16 floats at cols (t&3)*16 ----
    const int R = t >> 2, q = t & 3;
    const float* xs = x + (size_t)(row0 + R) * DDIM + q * 16;
    const int kk = q >> 1, lqa = (q & 1) * 2;       // K-chunk, lq-slot of first 8
    const int awr0 = kk * 4096 + (R >> 4) * 512 + ((R & 15) + 16 * lqa) * 8;
    // second 8 floats -> lq+1 -> +128 shorts

    f32x4 acc[4][4];
#pragma unroll
    for (int m = 0; m < 4; ++m)
#pragma unroll
        for (int n = 0; n < 4; ++n) acc[m][n] = (f32x4){0.f,0.f,0.f,0.f};
    float x2p = 0.f;
    float4 Xa0, Xa1, Xa2, Xa3;                      // one slab in flight (16 regs)

#define GLDS(TT, BUFI)                                               \
    {  const short* src_ = wsB + (size_t)(TT) * BTILE;               \
       glds16(src_ + t * 8,        &lB4[BUFI][0] + t * 8);           \
       glds16(src_ + 4096 + t * 8, &lB4[BUFI][0] + 4096 + t * 8); }

#define LOADX(SLAB)                                                  \
    {  Xa0 = *(const float4*)(xs + (SLAB) * 64);                     \
       Xa1 = *(const float4*)(xs + (SLAB) * 64 + 4);                 \
       Xa2 = *(const float4*)(xs + (SLAB) * 64 + 8);                 \
       Xa3 = *(const float4*)(xs + (SLAB) * 64 + 12); }

#define CVT()                                                                    \
    {  short8v s0, s1;                                                           \
       s0[0]=f2bf(Xa0.x); s0[1]=f2bf(Xa0.y); s0[2]=f2bf(Xa0.z); s0[3]=f2bf(Xa0.w);\
       s0[4]=f2bf(Xa1.x); s0[5]=f2bf(Xa1.y); s0[6]=f2bf(Xa1.z); s0[7]=f2bf(Xa1.w);\
       s1[0]=f2bf(Xa2.x); s1[1]=f2bf(Xa2.y); s1[2]=f2bf(Xa2.z); s1[3]=f2bf(Xa2.w);\
       s1[4]=f2bf(Xa3.x); s1[5]=f2bf(Xa3.y); s1[6]=f2bf(Xa3.z); s1[7]=f2bf(Xa3.w);\
       x2p += Xa0.x*Xa0.x + Xa0.y*Xa0.y + Xa0.z*Xa0.z + Xa0.w*Xa0.w              \
            + Xa1.x*Xa1.x + Xa1.y*Xa1.y + Xa1.z*Xa1.z + Xa1.w*Xa1.w              \
            + Xa2.x*Xa2.x + Xa2.y*Xa2.y + Xa2.z*Xa2.z + Xa2.w*Xa2.w              \
            + Xa3.x*Xa3.x + Xa3.y*Xa3.y + Xa3.z*Xa3.z + Xa3.w*Xa3.w;             \
       *(short8v*)&lA[awr0]       = s0;                                          \
       *(short8v*)&lA[awr0 + 128] = s1; }

#define MHALF(CC, BUFI)                                                          \
    {  short8v a0 = *(const short8v*)&lA[(CC)*4096 + (rg*4+0)*512 + lane*8];     \
       short8v a1 = *(const short8v*)&lA[(CC)*4096 + (rg*4+1)*512 + lane*8];     \
       short8v a2 = *(const short8v*)&lA[(CC)*4096 + (rg*4+2)*512 + lane*8];     \
       short8v a3 = *(const short8v*)&lA[(CC)*4096 + (rg*4+3)*512 + lane*8];     \
       short8v b0 = *(const short8v*)&lB4[BUFI][cg*2048 + lane*8];               \
       short8v b1 = *(const short8v*)&lB4[BUFI][cg*2048 + 512  + lane*8];        \
       short8v b2 = *(const short8v*)&lB4[BUFI][cg*2048 + 1024 + lane*8];        \
       short8v b3 = *(const short8v*)&lB4[BUFI][cg*2048 + 1536 + lane*8];        \
       acc[0][0] = __builtin_amdgcn_mfma_f32_16x16x32_bf16(a0, b0, acc[0][0], 0,0,0); \
       acc[0][1] = __builtin_amdgcn_mfma_f32_16x16x32_bf16(a0, b1, acc[0][1], 0,0,0); \
       acc[0][2] = __builtin_amdgcn_mfma_f32_16x16x32_bf16(a0, b2, acc[0][2], 0,0,0); \
       acc[0][3] = __builtin_amdgcn_mfma_f32_16x16x32_bf16(a0, b3, acc[0][3], 0,0,0); \
       acc[1][0] = __builtin_amdgcn_mfma_f32_16x16x32_bf16(a1, b0, acc[1][0], 0,0,0); \
       acc[1][1] = __builtin_amdgcn_mfma_f32_16x16x32_bf16(a1, b1, acc[1][1], 0,0,0); \
       acc[1][2] = __builtin_amdgcn_mfma_f32_16x16x32_bf16(a1, b2, acc[1][2], 0,0,0); \
       acc[1][3] = __builtin_amdgcn_mfma_f32_16x16x32_bf16(a1, b3, acc[1][3], 0,0,0); \
       acc[2][0] = __builtin_amdgcn_mfma_f32_16x16x32_bf16(a2, b0, acc[2][0], 0,0,0); \
       acc[2][1] = __builtin_amdgcn_mfma_f32_16x16x32_bf16(a2, b1, acc[2][1], 0,0,0); \
       acc[2][2] = __builtin_amdgcn_mfma_f32_16x16x32_bf16(a2, b2, acc[2][2], 0,0,0); \
       acc[2][3] = __builtin_amdgcn_mfma_f32_16x16x32_bf16(a2, b3, acc[2][3], 0,0,0); \
       acc[3][0] = __builtin_amdgcn_mfma_f32_16x16x32_bf16(a3, b0, acc[3][0], 0,0,0); \
       acc[3][1] = __builtin_amdgcn_mfma_f32_16x16x32_bf16(a3, b1, acc[3][1], 0,0,0); \
       acc[3][2] = __builtin_amdgcn_mfma_f32_16x16x32_bf16(a3, b2, acc[3][2], 0,0,0); \
       acc[3][3] = __builtin_amdgcn_mfma_f32_16x16x32_bf16(a3, b3, acc[3][3], 0,0,0); }

    // ITER(J): consume bufs (C0,C1); prefetch images (2J+2,2J+3) into (N0,N1).
#define ITER(J, C0, C1, N0, N1)                                                  \
    {  if ((J) + 1 < 8) { LOADX((J) + 1); }                                      \
       SFENCE();                                                                 \
       if ((J) < 7) { GLDS(2*(J)+2, N0); GLDS(2*(J)+3, N1); }                    \
       SFENCE();                                                                 \
       MHALF(0, C0);                                                             \
       MHALF(1, C1);                                                             \
       BARLGKM();                                                                \
       if ((J) + 1 < 8) { CVT(); }                                               \
       if ((J) < 7) { BARV0(); }                                                 \
       SFENCE(); }

    // ---- prologue: X(0); B images 0,1; cvt slab 0; drain ----
    LOADX(0);  SFENCE();
    GLDS(0, 0); GLDS(1, 1);  SFENCE();
    CVT();                    // waits only X(0) (oldest); B DMAs stay
    SFENCE();
    BARV0();                  // one-time startup drain of B(0),B(1)
    SFENCE();

    ITER(0, 0, 1, 2, 3)
    ITER(1, 2, 3, 0, 1)
    ITER(2, 0, 1, 2, 3)
    ITER(3, 2, 3, 0, 1)
    ITER(4, 0, 1, 2, 3)
    ITER(5, 2, 3, 0, 1)
    ITER(6, 0, 1, 2, 3)
    ITER(7, 2, 3, 0, 1)       // last: MHALFs + BARLGKM only

    // ---- ||x||^2: 4 staging threads per row ----
    x2p += __shfl_xor(x2p, 1); x2p += __shfl_xor(x2p, 2);
    if (q == 0) s_x2[R] = x2p;
    __syncthreads();

    // ---- epilogue: d2 -> q_unnorm (C/D: col=l15, row=lq*4+r) ----
    float c2a[4];
#pragma unroll
    for (int n = 0; n < 4; ++n) c2a[n] = wsC2[cg*64 + n*16 + l15];

#pragma unroll
    for (int m = 0; m < 4; ++m)
#pragma unroll
        for (int n = 0; n < 4; ++n)
#pragma unroll
            for (int r = 0; r < 4; ++r) {
                const int rw = rg*64 + m*16 + lq*4 + r;
                float d2 = fmaxf(s_x2[rw] + c2a[n] - 2.0f * acc[m][n][r], 0.0f);
                acc[m][n][r] = 1.0f / (1.0f + d2);
            }

    // ---- row sums: 16-lane shuffle, per-cg slot (deterministic) ----
#pragma unroll
    for (int m = 0; m < 4; ++m)
#pragma unroll
        for (int r = 0; r < 4; ++r) {
            float p = acc[m][0][r] + acc[m][1][r] + acc[m][2][r] + acc[m][3][r];
            p += __shfl_xor(p, 1); p += __shfl_xor(p, 2);
            p += __shfl_xor(p, 4); p += __shfl_xor(p, 8);
            if (l15 == 0) s_rs[cg*BM + rg*64 + m*16 + lq*4 + r] = p;
        }
    __syncthreads();

    // ---- normalize + store ----
#pragma unroll
    for (int m = 0; m < 4; ++m)
#pragma unroll
        for (int r = 0; r < 4; ++r) {
            const int rw = rg*64 + m*16 + lq*4 + r;
            const float rinv = 1.0f / (s_rs[rw] + s_rs[BM + rw]
                                     + s_rs[2*BM + rw] + s_rs[3*BM + rw]);
            float* o = out + (size_t)(row0 + rw) * KCL + cg*64 + l15;
#pragma unroll
            for (int n = 0; n < 4; ++n)
                o[n * 16] = acc[m][n][r] * rinv;
        }
}

extern "C" void kernel_launch(void* const* d_in, const int* in_sizes, int n_in,
                              void* d_out, int out_size, void* d_ws, size_t ws_size,
                              hipStream_t stream) {
    const float* x  = (const float*)d_in[0];
    const float* cl = (const float*)d_in[1];
    float* out = (float*)d_out;
    short* wsB  = (short*)d_ws;
    float* wsC2 = (float*)((char*)d_ws + (size_t)NIMG * BTILE * sizeof(short)); // +256 KB

    prep<<<80, 256, 0, stream>>>(cl, wsB, wsC2);
    const int B = in_sizes[0] / DDIM;     // 65536
    dec_main<<<B / BM, NT, 0, stream>>>(x, wsB, wsC2, out);
}

// Round 13
// 60.258 us; speedup vs baseline: 1.2774x; 1.2774x over previous
//
#include <hip/hip_runtime.h>
#include <hip/hip_bf16.h>

// DEC ClusteringLayer: q[i][j] = (1/(1+||x_i-c_j||^2)) / rowsum, ALPHA=1.
// Round 13: ZERO-REGISTER STAGING + 3 blocks/CU.
//  - x DMA'd into LDS as raw fp32 via global_load_lds (no X regs, no CVT pass,
//    no spill possible); converted to bf16 fragments at LDS-read time in MSTEP.
//  - BM=64, NT=256 (4 waves x 64x64, full 256 cols -> fused row-normalize).
//    LDS ~49.5KB -> 3 independent blocks/CU: when one block waits at its
//    barrier, two others run (attacks the measured convoy stalls).
//  - One vmcnt(0)+lgkm(0) barrier per iter (16 total); dbuf A and B.
//  - A fp32 LDS layout [mb][half][lane][4]: DMA writes AND ds_read_b128 both
//    contiguous 16B/lane -> conflict-free.

typedef __attribute__((ext_vector_type(8))) short short8v;
typedef __attribute__((ext_vector_type(4))) float f32x4;

#define DDIM 512
#define KCL  256
#define BM   64
#define NT   256
#define NTILES 16
#define BTILE  8192      // shorts per fragment-order B image (256 x 32)

__device__ __forceinline__ short f2bf(float f) {
    __hip_bfloat16 h = __float2bfloat16(f);
    return __builtin_bit_cast(short, h);
}

__device__ __forceinline__ void glds16(const void* g, void* l) {
    __builtin_amdgcn_global_load_lds(
        (const __attribute__((address_space(1))) unsigned int*)g,
        (__attribute__((address_space(3))) unsigned int*)l, 16, 0, 0);
}

// ---- pre-kernel: blocks 0..63 pack clusters -> bf16 fragment-order images;
//      blocks 64..79 compute ||c||^2 ----
__global__ void prep(const float* __restrict__ cl, short* __restrict__ wsB,
                     float* __restrict__ wsC2) {
    const int t = threadIdx.x;
    if (blockIdx.x < 64) {
        const int u = blockIdx.x * 256 + t;
        const int img = u >> 10, gi = u & 1023;
        const int g = gi >> 6, lq = (gi >> 4) & 3, l15 = gi & 15;
        const float* src = cl + (size_t)(g * 16 + l15) * DDIM + img * 32 + lq * 8;
        float4 a = *(const float4*)src;
        float4 b = *(const float4*)(src + 4);
        short8v s;
        s[0]=f2bf(a.x); s[1]=f2bf(a.y); s[2]=f2bf(a.z); s[3]=f2bf(a.w);
        s[4]=f2bf(b.x); s[5]=f2bf(b.y); s[6]=f2bf(b.z); s[7]=f2bf(b.w);
        *(short8v*)&wsB[(size_t)u * 8] = s;
    } else {
        const int cidx = (blockIdx.x - 64) * 16 + (t >> 4);
        const int j = t & 15;
        const float* src = cl + (size_t)cidx * DDIM + j * 32;
        float s = 0.f;
#pragma unroll
        for (int i = 0; i < 8; ++i) {
            float4 v = ((const float4*)src)[i];
            s += v.x*v.x + v.y*v.y + v.z*v.z + v.w*v.w;
        }
        s += __shfl_xor(s, 1); s += __shfl_xor(s, 2);
        s += __shfl_xor(s, 4); s += __shfl_xor(s, 8);
        if (j == 0) wsC2[cidx] = s;
    }
}

#define SFENCE() __builtin_amdgcn_sched_barrier(0)
#define BARV0()  asm volatile("s_waitcnt vmcnt(0) lgkmcnt(0)\ns_barrier" ::: "memory")

__global__ __launch_bounds__(NT, 3)
void dec_main(const float* __restrict__ x, const short* __restrict__ wsB,
              const float* __restrict__ wsC2, float* __restrict__ out) {
    __shared__ __align__(16) short lBd[2][BTILE];   // 32 KB: B images (bf16)
    __shared__ __align__(16) float lAf[2][2048];    // 16 KB: A tiles (raw fp32)
    __shared__ float s_x2[BM];
    __shared__ float s_rs[4][BM];

    const int t = threadIdx.x, lane = t & 63, w = t >> 6;   // w = cg (0..3)
    const int cg = w;
    const int l15 = lane & 15, lq = lane >> 4;
    const int row0 = blockIdx.x * BM;

    // ---- A-DMA source mapping (thread t, 2 calls of 16B) ----
    // LDS layout: float slot = mb*512 + half*256 + lane*4 + j
    //   row = mb*16 + (lane&15), col = (lane>>4)*8 + half*4 + j
    // call0 slot = 4t -> mb=t>>7, lane=t&63, half=(t>>6)&1; call1 slot = 4t+1024 -> mb+2
    const int rA = ((t >> 7) << 4) + (t & 15);
    const int cA = (((t >> 4) & 3) << 3) + (((t >> 6) & 1) << 2);
    const float* ga0 = x + (size_t)(row0 + rA) * DDIM + cA;
    const float* ga1 = x + (size_t)(row0 + rA + 32) * DDIM + cA;

    f32x4 acc[4][4];
#pragma unroll
    for (int m = 0; m < 4; ++m)
#pragma unroll
        for (int n = 0; n < 4; ++n) acc[m][n] = (f32x4){0.f,0.f,0.f,0.f};
    float x2p[4] = {0.f, 0.f, 0.f, 0.f};

#define GLDSA(TT, P)                                                 \
    {  glds16(ga0 + (TT) * 32, &lAf[P][t * 4]);                      \
       glds16(ga1 + (TT) * 32, &lAf[P][t * 4 + 1024]); }

#define GLDSB(TT, P)                                                 \
    {  const short* s_ = wsB + (size_t)(TT) * BTILE;                 \
       short* d_ = &lBd[P][0];                                       \
       glds16(s_ + t * 8,        d_ + t * 8);                        \
       glds16(s_ + 2048 + t * 8, d_ + 2048 + t * 8);                 \
       glds16(s_ + 4096 + t * 8, d_ + 4096 + t * 8);                 \
       glds16(s_ + 6144 + t * 8, d_ + 6144 + t * 8); }

#define MSTEP(P)                                                                 \
    {  short8v b0 = *(const short8v*)&lBd[P][(cg*4+0)*512 + lane*8];             \
       short8v b1 = *(const short8v*)&lBd[P][(cg*4+1)*512 + lane*8];             \
       short8v b2 = *(const short8v*)&lBd[P][(cg*4+2)*512 + lane*8];             \
       short8v b3 = *(const short8v*)&lBd[P][(cg*4+3)*512 + lane*8];             \
       _Pragma("unroll")                                                         \
       for (int m = 0; m < 4; ++m) {                                             \
           float4 alo = *(const float4*)&lAf[P][m*512 + lane*4];                 \
           float4 ahi = *(const float4*)&lAf[P][m*512 + 256 + lane*4];           \
           short8v af;                                                           \
           af[0]=f2bf(alo.x); af[1]=f2bf(alo.y); af[2]=f2bf(alo.z); af[3]=f2bf(alo.w); \
           af[4]=f2bf(ahi.x); af[5]=f2bf(ahi.y); af[6]=f2bf(ahi.z); af[7]=f2bf(ahi.w); \
           if (w == 0)                                                           \
               x2p[m] += alo.x*alo.x + alo.y*alo.y + alo.z*alo.z + alo.w*alo.w   \
                       + ahi.x*ahi.x + ahi.y*ahi.y + ahi.z*ahi.z + ahi.w*ahi.w;  \
           acc[m][0] = __builtin_amdgcn_mfma_f32_16x16x32_bf16(af, b0, acc[m][0], 0,0,0); \
           acc[m][1] = __builtin_amdgcn_mfma_f32_16x16x32_bf16(af, b1, acc[m][1], 0,0,0); \
           acc[m][2] = __builtin_amdgcn_mfma_f32_16x16x32_bf16(af, b2, acc[m][2], 0,0,0); \
           acc[m][3] = __builtin_amdgcn_mfma_f32_16x16x32_bf16(af, b3, acc[m][3], 0,0,0); \
       } }

#define ITER(J)                                                                  \
    {  if ((J) + 1 < NTILES) { GLDSA((J)+1, ((J)+1)&1); GLDSB((J)+1, ((J)+1)&1); } \
       SFENCE();                                                                 \
       MSTEP((J)&1);                                                             \
       if ((J) + 1 < NTILES) { BARV0(); }                                        \
       SFENCE(); }

    // ---- prologue: tile 0 DMA, drain ----
    GLDSA(0, 0); GLDSB(0, 0);
    BARV0();
    SFENCE();

    ITER( 0) ITER( 1) ITER( 2) ITER( 3)
    ITER( 4) ITER( 5) ITER( 6) ITER( 7)
    ITER( 8) ITER( 9) ITER(10) ITER(11)
    ITER(12) ITER(13) ITER(14) ITER(15)

    // ---- ||x||^2: computed by wave 0 during MSTEP; reduce over lq lanes ----
#pragma unroll
    for (int m = 0; m < 4; ++m) {
        float v = x2p[m];
        v += __shfl_xor(v, 16); v += __shfl_xor(v, 32);
        if (w == 0 && lq == 0) s_x2[m*16 + l15] = v;
    }
    __syncthreads();

    // ---- epilogue: d2 -> q_unnorm (C/D: col=l15, row=lq*4+r) ----
    float c2a[4];
#pragma unroll
    for (int n = 0; n < 4; ++n) c2a[n] = wsC2[cg*64 + n*16 + l15];

#pragma unroll
    for (int m = 0; m < 4; ++m)
#pragma unroll
        for (int n = 0; n < 4; ++n)
#pragma unroll
            for (int r = 0; r < 4; ++r) {
                const int rw = m*16 + lq*4 + r;
                float d2 = fmaxf(s_x2[rw] + c2a[n] - 2.0f * acc[m][n][r], 0.0f);
                acc[m][n][r] = 1.0f / (1.0f + d2);
            }

    // ---- row sums: 16-lane shuffle, per-cg slot (deterministic) ----
#pragma unroll
    for (int m = 0; m < 4; ++m)
#pragma unroll
        for (int r = 0; r < 4; ++r) {
            float p = acc[m][0][r] + acc[m][1][r] + acc[m][2][r] + acc[m][3][r];
            p += __shfl_xor(p, 1); p += __shfl_xor(p, 2);
            p += __shfl_xor(p, 4); p += __shfl_xor(p, 8);
            if (l15 == 0) s_rs[cg][m*16 + lq*4 + r] = p;
        }
    __syncthreads();

    // ---- normalize + store ----
#pragma unroll
    for (int m = 0; m < 4; ++m)
#pragma unroll
        for (int r = 0; r < 4; ++r) {
            const int rw = m*16 + lq*4 + r;
            const float rinv = 1.0f / (s_rs[0][rw] + s_rs[1][rw] + s_rs[2][rw] + s_rs[3][rw]);
            float* o = out + (size_t)(row0 + rw) * KCL + cg*64 + l15;
#pragma unroll
            for (int n = 0; n < 4; ++n)
                o[n * 16] = acc[m][n][r] * rinv;
        }
}

extern "C" void kernel_launch(void* const* d_in, const int* in_sizes, int n_in,
                              void* d_out, int out_size, void* d_ws, size_t ws_size,
                              hipStream_t stream) {
    const float* x  = (const float*)d_in[0];
    const float* cl = (const float*)d_in[1];
    float* out = (float*)d_out;
    short* wsB  = (short*)d_ws;
    float* wsC2 = (float*)((char*)d_ws + (size_t)NTILES * BTILE * sizeof(short)); // +256 KB

    prep<<<80, 256, 0, stream>>>(cl, wsB, wsC2);
    const int B = in_sizes[0] / DDIM;     // 65536
    dec_main<<<B / BM, NT, 0, stream>>>(x, wsB, wsC2, out);
}

// Round 14
// 50.192 us; speedup vs baseline: 1.5336x; 1.2006x over previous
//
#include <hip/hip_runtime.h>
#include <hip/hip_bf16.h>

// DEC ClusteringLayer: q[i][j] = (1/(1+||x_i-c_j||^2)) / rowsum, ALPHA=1.
// Round 14 = R11 geometry + R13 zero-reg staging + latency-matched prefetch:
//  - BM=128, NT=512, 2 blocks/CU (LDS exactly 80KB).
//  - A (x, HBM ~900cy): fp32 global_load_lds, TRI-buffered -> every drained
//    A-DMA has 2 MSTEP-intervals of cover. cvt fp32->bf16 at LDS-read in MSTEP.
//  - B (clusters, L2 ~250cy): bf16 fragment images, DOUBLE-buffered, 1 interval.
//  - Per-iter issue order B(J+1) then A(J+2); barrier waits vmcnt(2) =
//    drains exactly {A(J+1), B(J+1)}, leaves A(J+2) in flight. No full drains
//    in the loop. Zero register prefetch state -> no spill possible.

typedef __attribute__((ext_vector_type(8))) short short8v;
typedef __attribute__((ext_vector_type(4))) float f32x4;

#define DDIM 512
#define KCL  256
#define BM   128
#define NT   512
#define NTILES 16
#define BTILE  8192      // shorts per fragment-order B image (256 x 32)

__device__ __forceinline__ short f2bf(float f) {
    __hip_bfloat16 h = __float2bfloat16(f);
    return __builtin_bit_cast(short, h);
}

__device__ __forceinline__ void glds16(const void* g, void* l) {
    __builtin_amdgcn_global_load_lds(
        (const __attribute__((address_space(1))) unsigned int*)g,
        (__attribute__((address_space(3))) unsigned int*)l, 16, 0, 0);
}

// ---- pre-kernel: blocks 0..63 pack clusters -> bf16 fragment-order images;
//      blocks 64..79 compute ||c||^2 ----
__global__ void prep(const float* __restrict__ cl, short* __restrict__ wsB,
                     float* __restrict__ wsC2) {
    const int t = threadIdx.x;
    if (blockIdx.x < 64) {
        const int u = blockIdx.x * 256 + t;
        const int img = u >> 10, gi = u & 1023;
        const int g = gi >> 6, lq = (gi >> 4) & 3, l15 = gi & 15;
        const float* src = cl + (size_t)(g * 16 + l15) * DDIM + img * 32 + lq * 8;
        float4 a = *(const float4*)src;
        float4 b = *(const float4*)(src + 4);
        short8v s;
        s[0]=f2bf(a.x); s[1]=f2bf(a.y); s[2]=f2bf(a.z); s[3]=f2bf(a.w);
        s[4]=f2bf(b.x); s[5]=f2bf(b.y); s[6]=f2bf(b.z); s[7]=f2bf(b.w);
        *(short8v*)&wsB[(size_t)u * 8] = s;
    } else {
        const int cidx = (blockIdx.x - 64) * 16 + (t >> 4);
        const int j = t & 15;
        const float* src = cl + (size_t)cidx * DDIM + j * 32;
        float s = 0.f;
#pragma unroll
        for (int i = 0; i < 8; ++i) {
            float4 v = ((const float4*)src)[i];
            s += v.x*v.x + v.y*v.y + v.z*v.z + v.w*v.w;
        }
        s += __shfl_xor(s, 1); s += __shfl_xor(s, 2);
        s += __shfl_xor(s, 4); s += __shfl_xor(s, 8);
        if (j == 0) wsC2[cidx] = s;
    }
}

#define SFENCE() __builtin_amdgcn_sched_barrier(0)
#define BARV2()  asm volatile("s_waitcnt vmcnt(2) lgkmcnt(0)\ns_barrier" ::: "memory")
#define BARV0()  asm volatile("s_waitcnt vmcnt(0) lgkmcnt(0)\ns_barrier" ::: "memory")

__global__ __launch_bounds__(NT, 4)
void dec_main(const float* __restrict__ x, const short* __restrict__ wsB,
              const float* __restrict__ wsC2, float* __restrict__ out) {
    __shared__ __align__(16) float lAf[3][4096];   // 48 KB: A tiles, raw fp32, tri-buf
    __shared__ __align__(16) short lBd[2][BTILE];  // 32 KB: B images, dbuf
    float* const s_x2 = &lAf[0][0];                // aliased post-loop
    float* const s_rs = &lAf[0][0] + BM;           // 4 x 128 floats

    const int t = threadIdx.x, lane = t & 63, w = t >> 6;
    const int rg = w >> 2, cg = w & 3;             // 2 row-groups x 4 col-groups
    const int l15 = lane & 15, lq = lane >> 4;
    const int row0 = blockIdx.x * BM;

    // ---- A-DMA mapping: thread t, 2 calls of 16B per tile ----
    // LDS float slot = mb*512 + half*256 + l*4 ; row = mb*16 + (l&15),
    // col = (l>>4)*8 + half*4. call0: slot=4t (mb=t>>7); call1: +2048 (mb+4).
    const int rA = ((t >> 7) << 4) + (t & 15);
    const int cA = (((t >> 4) & 3) << 3) + (((t >> 6) & 1) << 2);
    const float* ga0 = x + (size_t)(row0 + rA) * DDIM + cA;        // rows 0..63
    const float* ga1 = x + (size_t)(row0 + rA + 64) * DDIM + cA;   // rows 64..127

    f32x4 acc[4][4];
#pragma unroll
    for (int m = 0; m < 4; ++m)
#pragma unroll
        for (int n = 0; n < 4; ++n) acc[m][n] = (f32x4){0.f,0.f,0.f,0.f};
    float x2p[4] = {0.f, 0.f, 0.f, 0.f};

#define GLDSA(TT, P)                                                 \
    {  glds16(ga0 + (TT) * 32, &lAf[P][t * 4]);                      \
       glds16(ga1 + (TT) * 32, &lAf[P][t * 4 + 2048]); }

#define GLDSB(TT, P)                                                 \
    {  const short* s_ = wsB + (size_t)(TT) * BTILE;                 \
       glds16(s_ + t * 8,        &lBd[P][t * 8]);                    \
       glds16(s_ + 4096 + t * 8, &lBd[P][4096 + t * 8]); }

#define MSTEP(AP, BP)                                                            \
    {  short8v b0 = *(const short8v*)&lBd[BP][(cg*4+0)*512 + lane*8];            \
       short8v b1 = *(const short8v*)&lBd[BP][(cg*4+1)*512 + lane*8];            \
       short8v b2 = *(const short8v*)&lBd[BP][(cg*4+2)*512 + lane*8];            \
       short8v b3 = *(const short8v*)&lBd[BP][(cg*4+3)*512 + lane*8];            \
       _Pragma("unroll")                                                         \
       for (int m = 0; m < 4; ++m) {                                             \
           float4 alo = *(const float4*)&lAf[AP][(rg*4+m)*512 + lane*4];         \
           float4 ahi = *(const float4*)&lAf[AP][(rg*4+m)*512 + 256 + lane*4];   \
           short8v af;                                                           \
           af[0]=f2bf(alo.x); af[1]=f2bf(alo.y); af[2]=f2bf(alo.z); af[3]=f2bf(alo.w); \
           af[4]=f2bf(ahi.x); af[5]=f2bf(ahi.y); af[6]=f2bf(ahi.z); af[7]=f2bf(ahi.w); \
           if (cg == 0)                                                          \
               x2p[m] += alo.x*alo.x + alo.y*alo.y + alo.z*alo.z + alo.w*alo.w   \
                       + ahi.x*ahi.x + ahi.y*ahi.y + ahi.z*ahi.z + ahi.w*ahi.w;  \
           acc[m][0] = __builtin_amdgcn_mfma_f32_16x16x32_bf16(af, b0, acc[m][0], 0,0,0); \
           acc[m][1] = __builtin_amdgcn_mfma_f32_16x16x32_bf16(af, b1, acc[m][1], 0,0,0); \
           acc[m][2] = __builtin_amdgcn_mfma_f32_16x16x32_bf16(af, b2, acc[m][2], 0,0,0); \
           acc[m][3] = __builtin_amdgcn_mfma_f32_16x16x32_bf16(af, b3, acc[m][3], 0,0,0); \
       } }

    // ITER(J): issue B(J+1) then A(J+2); MSTEP(J); barrier vmcnt(2) drains
    // exactly {A(J+1) [2 intervals old], B(J+1) [1 interval]}, keeps A(J+2).
#define ITER(J, AC, AN, BC, BN)                                                  \
    {  if ((J) + 1 < NTILES) { GLDSB((J)+1, BN); }                               \
       if ((J) + 2 < NTILES) { GLDSA((J)+2, AN); }                               \
       SFENCE();                                                                 \
       MSTEP(AC, BC);                                                            \
       SFENCE();                                                                 \
       if ((J) + 2 < NTILES) { BARV2(); }                                        \
       else if ((J) + 1 < NTILES) { BARV0(); }                                   \
       SFENCE(); }

    // ---- prologue: A(0), B(0), A(1) in flight; drain A(0)+B(0), keep A(1) ----
    GLDSA(0, 0);
    GLDSB(0, 0);
    GLDSA(1, 1);
    SFENCE();
    BARV2();
    SFENCE();

    ITER( 0, 0, 2, 0, 1)
    ITER( 1, 1, 0, 1, 0)
    ITER( 2, 2, 1, 0, 1)
    ITER( 3, 0, 2, 1, 0)
    ITER( 4, 1, 0, 0, 1)
    ITER( 5, 2, 1, 1, 0)
    ITER( 6, 0, 2, 0, 1)
    ITER( 7, 1, 0, 1, 0)
    ITER( 8, 2, 1, 0, 1)
    ITER( 9, 0, 2, 1, 0)
    ITER(10, 1, 0, 0, 1)
    ITER(11, 2, 1, 1, 0)
    ITER(12, 0, 2, 0, 1)
    ITER(13, 1, 0, 1, 0)
    ITER(14, 2, 1, 0, 1)
    ITER(15, 0, 0, 1, 1)      // MSTEP only (guards skip issues/barriers)

    // ---- ||x||^2 publish (aliases lAf[0]; barrier first) ----
    __syncthreads();
#pragma unroll
    for (int m = 0; m < 4; ++m) {
        float v = x2p[m];
        v += __shfl_xor(v, 16); v += __shfl_xor(v, 32);
        if (cg == 0 && lq == 0) s_x2[rg*64 + m*16 + l15] = v;
    }
    __syncthreads();

    // ---- epilogue: d2 -> q_unnorm (C/D: col=l15, row=lq*4+r) ----
    float c2a[4];
#pragma unroll
    for (int n = 0; n < 4; ++n) c2a[n] = wsC2[cg*64 + n*16 + l15];

#pragma unroll
    for (int m = 0; m < 4; ++m)
#pragma unroll
        for (int n = 0; n < 4; ++n)
#pragma unroll
            for (int r = 0; r < 4; ++r) {
                const int rw = rg*64 + m*16 + lq*4 + r;
                float d2 = fmaxf(s_x2[rw] + c2a[n] - 2.0f * acc[m][n][r], 0.0f);
                acc[m][n][r] = 1.0f / (1.0f + d2);
            }

    // ---- row sums: 16-lane shuffle, per-cg slot (deterministic) ----
#pragma unroll
    for (int m = 0; m < 4; ++m)
#pragma unroll
        for (int r = 0; r < 4; ++r) {
            float p = acc[m][0][r] + acc[m][1][r] + acc[m][2][r] + acc[m][3][r];
            p += __shfl_xor(p, 1); p += __shfl_xor(p, 2);
            p += __shfl_xor(p, 4); p += __shfl_xor(p, 8);
            if (l15 == 0) s_rs[cg*BM + rg*64 + m*16 + lq*4 + r] = p;
        }
    __syncthreads();

    // ---- normalize + store ----
#pragma unroll
    for (int m = 0; m < 4; ++m)
#pragma unroll
        for (int r = 0; r < 4; ++r) {
            const int rw = rg*64 + m*16 + lq*4 + r;
            const float rinv = 1.0f / (s_rs[rw] + s_rs[BM + rw]
                                     + s_rs[2*BM + rw] + s_rs[3*BM + rw]);
            float* o = out + (size_t)(row0 + rw) * KCL + cg*64 + l15;
#pragma unroll
            for (int n = 0; n < 4; ++n)
                o[n * 16] = acc[m][n][r] * rinv;
        }
}

extern "C" void kernel_launch(void* const* d_in, const int* in_sizes, int n_in,
                              void* d_out, int out_size, void* d_ws, size_t ws_size,
                              hipStream_t stream) {
    const float* x  = (const float*)d_in[0];
    const float* cl = (const float*)d_in[1];
    float* out = (float*)d_out;
    short* wsB  = (short*)d_ws;
    float* wsC2 = (float*)((char*)d_ws + (size_t)NTILES * BTILE * sizeof(short)); // +256 KB

    prep<<<80, 256, 0, stream>>>(cl, wsB, wsC2);
    const int B = in_sizes[0] / DDIM;     // 65536
    dec_main<<<B / BM, NT, 0, stream>>>(x, wsB, wsC2, out);
}